// Round 6
// baseline (156.654 us; speedup 1.0000x reference)
//
#include <hip/hip_runtime.h>
#include <hip/hip_bf16.h>

#define B_ 4
#define T_ 2048
#define D_ 2048
#define DV_ 1024
#define TIMG_ 8
#define NLAT_ 64
#define H_ 16
#define DH_ 64
#define INNER_ 1024
#define J_ (TIMG_ * NLAT_)  // 512

using f32x4 = __attribute__((ext_vector_type(4))) float;
using bf16x8 = __attribute__((ext_vector_type(8))) short;
using bf16x4 = __attribute__((ext_vector_type(4))) short;

__device__ __forceinline__ unsigned short f2bf(float f) {
  union { float f; unsigned int u; } c{f};
  unsigned int r = c.u + 0x7FFFu + ((c.u >> 16) & 1u);  // RNE
  return (unsigned short)(r >> 16);
}

__device__ __forceinline__ void stage16(const unsigned short* g, unsigned short* l) {
  __builtin_amdgcn_global_load_lds(
      (const __attribute__((address_space(1))) unsigned int*)g,
      (__attribute__((address_space(3))) unsigned int*)l, 16, 0, 0);
}

// ================= fused prep v2: ln(wave/row) | scan | tcast 64x64 | cast =================
// grid: [0,2048) ln x4 rows; [2048,2052) scan; [2052,2564) Wq; [2564,3076) Wkv;
//       [3076,3588) Wout; [3588,4612) media cast.
__global__ __launch_bounds__(256) void prep_kernel(
    const float* __restrict__ x, const void* __restrict__ locs,
    const float* __restrict__ g, const float* __restrict__ bta,
    const float* __restrict__ Wq, const float* __restrict__ Wkv,
    const float* __restrict__ Wout, const float* __restrict__ media,
    unsigned short* __restrict__ xn, int* __restrict__ img_idx,
    unsigned short* __restrict__ wqt, unsigned short* __restrict__ wkvt,
    unsigned short* __restrict__ woutt, unsigned short* __restrict__ medb) {
  __shared__ __align__(16) float smf[64 * 68];  // tcast tile; scan reuses as int[256]
  const int tid = threadIdx.x;
  int blk = blockIdx.x;

  if (blk < 2048) {
    // ---------------- LayerNorm: one wave per row, no syncthreads ----------------
    const int lane = tid & 63;
    const int row = blk * 4 + (tid >> 6);
    const float4* xr = (const float4*)(x + (size_t)row * D_);
    float4 v[8];
#pragma unroll
    for (int i = 0; i < 8; ++i) v[i] = xr[i * 64 + lane];
    float s = 0.f, sq = 0.f;
#pragma unroll
    for (int i = 0; i < 8; ++i) {
      s += v[i].x + v[i].y + v[i].z + v[i].w;
      sq += v[i].x * v[i].x + v[i].y * v[i].y + v[i].z * v[i].z + v[i].w * v[i].w;
    }
#pragma unroll
    for (int off = 32; off > 0; off >>= 1) {
      s += __shfl_xor(s, off);
      sq += __shfl_xor(sq, off);
    }
    const float mu = s * (1.0f / D_);
    const float rstd = rsqrtf(sq * (1.0f / D_) - mu * mu + 1e-5f);
    const float4* gv4 = (const float4*)g;
    const float4* bv4 = (const float4*)bta;
    ushort4* o4 = (ushort4*)(xn + (size_t)row * D_);
#pragma unroll
    for (int i = 0; i < 8; ++i) {
      float4 gv = gv4[i * 64 + lane];
      float4 bv = bv4[i * 64 + lane];
      o4[i * 64 + lane] = make_ushort4(f2bf((v[i].x - mu) * rstd * gv.x + bv.x),
                                       f2bf((v[i].y - mu) * rstd * gv.y + bv.y),
                                       f2bf((v[i].z - mu) * rstd * gv.z + bv.z),
                                       f2bf((v[i].w - mu) * rstd * gv.w + bv.w));
    }
    return;
  }
  blk -= 2048;
  if (blk < 4) {
    // ---------------- media_locations scan ----------------
    int* sm = (int*)smf;
    const int b = blk;
    const unsigned char* u8 = (const unsigned char*)locs;
    int cnt = 0;
    for (int i = tid; i < B_ * T_; i += 256) cnt += (u8[i] != 0) ? 1 : 0;
    sm[tid] = cnt;
    __syncthreads();
    for (int off = 128; off > 0; off >>= 1) {
      if (tid < off) sm[tid] += sm[tid + off];
      __syncthreads();
    }
    const bool u8mode = (sm[0] == B_ * TIMG_);
    __syncthreads();
    const int base = b * T_ + tid * 8;
    const int* i32 = (const int*)locs;
    int v[8];
    int ts = 0;
#pragma unroll
    for (int j = 0; j < 8; ++j) {
      v[j] = u8mode ? (u8[base + j] != 0 ? 1 : 0) : (i32[base + j] != 0 ? 1 : 0);
      ts += v[j];
    }
    sm[tid] = ts;
    __syncthreads();
    for (int off = 1; off < 256; off <<= 1) {
      int add = (tid >= off) ? sm[tid - off] : 0;
      __syncthreads();
      sm[tid] += add;
      __syncthreads();
    }
    int acc = sm[tid] - ts;
#pragma unroll
    for (int j = 0; j < 8; ++j) {
      acc += v[j];
      img_idx[base + j] = acc - 1;
    }
    return;
  }
  blk -= 4;
  if (blk < 1536) {
    // ---------------- tcast 64x64: f32(RxC) -> bf16(CxR) ----------------
    const float* tin;
    unsigned short* tout;
    int R, C, bx, by;
    float scale = 1.0f;
    if (blk < 512) {            // Wq: R=2048, C=1024 -> 32 x 16 blocks
      tin = Wq; tout = wqt; R = D_; C = INNER_; by = blk >> 4; bx = blk & 15; scale = 0.125f;
    } else if (blk < 1024) {    // Wkv: R=1024, C=2048 -> 16 x 32
      blk -= 512;
      tin = Wkv; tout = wkvt; R = DV_; C = 2 * INNER_; by = blk >> 5; bx = blk & 31;
    } else {                    // Wout: R=1024, C=2048 -> 16 x 32
      blk -= 1024;
      tin = Wout; tout = woutt; R = INNER_; C = D_; by = blk >> 5; bx = blk & 31;
    }
    const int br = by * 64, bc = bx * 64;
    float (*tile)[68] = (float(*)[68])smf;  // row stride 272B = 17*16B: f32x4-aligned
    const int r = tid >> 4;          // 0..15
    const int c4 = (tid & 15) * 4;   // 0..60
#pragma unroll
    for (int rr = 0; rr < 4; ++rr)
      *(float4*)&tile[r + rr * 16][c4] =
          *(const float4*)&tin[(size_t)(br + r + rr * 16) * C + bc + c4];
    __syncthreads();
    const int oc = tid >> 2;         // 0..63 (src col = out row)
    const int rb = (tid & 3) * 16;   // 0,16,32,48
    bf16x8 o0, o1;
#pragma unroll
    for (int e = 0; e < 8; ++e) {
      o0[e] = (short)f2bf(tile[rb + e][oc] * scale);
      o1[e] = (short)f2bf(tile[rb + 8 + e][oc] * scale);
    }
    unsigned short* op = tout + (size_t)(bc + oc) * R + br + rb;
    *(bf16x8*)op = o0;
    *(bf16x8*)(op + 8) = o1;
    return;
  }
  blk -= 1536;
  // ---------------- media cast: 2 float4 per thread ----------------
  const int i = blk * 512 + tid * 2;
  float4 a = ((const float4*)media)[i];
  float4 b2 = ((const float4*)media)[i + 1];
  ((ushort4*)medb)[i] = make_ushort4(f2bf(a.x), f2bf(a.y), f2bf(a.z), f2bf(a.w));
  ((ushort4*)medb)[i + 1] = make_ushort4(f2bf(b2.x), f2bf(b2.y), f2bf(b2.z), f2bf(b2.w));
}

// ---------------- bf16->bf16 transpose of V half of kv: vt[b][d][j] ----------------
__global__ void vtrans(const unsigned short* __restrict__ kvb, unsigned short* __restrict__ vt) {
  __shared__ unsigned short tile[32][33];
  const int jt = blockIdx.x * 32;
  const int dt = blockIdx.y * 32;
  const int b = blockIdx.z;
  const int tx = threadIdx.x, ty = threadIdx.y;
#pragma unroll
  for (int i = ty; i < 32; i += 8)
    tile[i][tx] = kvb[(size_t)(b * J_ + jt + i) * (2 * INNER_) + INNER_ + dt + tx];
  __syncthreads();
#pragma unroll
  for (int i = ty; i < 32; i += 8)
    vt[(size_t)(b * INNER_ + dt + i) * J_ + jt + tx] = tile[tx][i];
}

// ============ v2 128x256 2-phase GEMM: A dbuf + B tri-buf, 1 vmcnt/K-tile ============
template <bool BF16OUT>
__global__ __launch_bounds__(512, 2) void gemm_bt2(const unsigned short* __restrict__ Ag,
                                                   const unsigned short* __restrict__ Bg,
                                                   void* __restrict__ Cv,
                                                   int M, int N, int K) {
  __shared__ __align__(16) unsigned short lds[65536];  // 128 KB
  const int tid = threadIdx.x;
  const int lane = tid & 63;
  const int wave = tid >> 6;
  const int l15 = lane & 15;
  const int lg8 = (lane >> 4) << 3;
  const int wr64 = (wave >> 2) << 6;
  const int wc16 = (wave & 3) << 4;

  const int nwg = gridDim.x;
  int wg = ((int)blockIdx.x & 7) * (nwg >> 3) + ((int)blockIdx.x >> 3);
  const int gridM = M >> 7;
  const long row0 = (long)(wg % gridM) << 7;
  const long col0 = (long)(wg / gridM) << 8;

  auto stA = [&](int t, int r) {
    const int i = r * 512 + tid;
    const int row = i >> 3;
    const int c = (i & 7) ^ (row & 7);
    stage16(Ag + (size_t)(row0 + row) * K + (t << 6) + c * 8,
            &lds[(t & 1) * 8192 + i * 8]);
  };
  auto stB = [&](int t, int r) {
    const int i = r * 512 + tid;
    const int row = i >> 3;
    const int c = (i & 7) ^ (row & 7);
    stage16(Bg + (size_t)(col0 + row) * K + (t << 6) + c * 8,
            &lds[16384 + (t % 3) * 16384 + i * 8]);
  };

  const int NT = K >> 6;
  stB(0, 0); stB(0, 1); stB(0, 2); stB(0, 3);
  stA(0, 0); stA(0, 1);
  stB(1, 0); stB(1, 1); stB(1, 2); stB(1, 3);
  asm volatile("s_waitcnt vmcnt(4)" ::: "memory");
  asm volatile("s_barrier" ::: "memory");

  f32x4 acc[4][4] = {};
  for (int t = 0; t < NT; ++t) {
    const unsigned short* Ab = &lds[(t & 1) * 8192];
    const unsigned short* Bb = &lds[16384 + (t % 3) * 16384];
    bf16x8 af[4][2], bfr[4][2];
    // ---------- P1 ----------
#pragma unroll
    for (int m = 0; m < 4; ++m)
#pragma unroll
      for (int kk = 0; kk < 2; ++kk) {
        const int row = wr64 + m * 16 + l15;
        af[m][kk] = *(const bf16x8*)(Ab + row * 64 + ((kk * 32 + lg8) ^ ((row & 7) << 3)));
      }
#pragma unroll
    for (int n = 0; n < 2; ++n)
#pragma unroll
      for (int kk = 0; kk < 2; ++kk) {
        const int brow = n * 64 + wc16 + l15;
        bfr[n][kk] = *(const bf16x8*)(Bb + brow * 64 + ((kk * 32 + lg8) ^ ((brow & 7) << 3)));
      }
    if (t + 1 < NT) { stA(t + 1, 0); stA(t + 1, 1); }
    if (t + 2 < NT) { stB(t + 2, 0); stB(t + 2, 1); }
    asm volatile("s_barrier" ::: "memory");
    asm volatile("s_waitcnt lgkmcnt(0)" ::: "memory");
    __builtin_amdgcn_s_setprio(1);
#pragma unroll
    for (int m = 0; m < 4; ++m)
#pragma unroll
      for (int n = 0; n < 2; ++n)
#pragma unroll
        for (int kk = 0; kk < 2; ++kk)
          acc[m][n] = __builtin_amdgcn_mfma_f32_16x16x32_bf16(af[m][kk], bfr[n][kk], acc[m][n], 0, 0, 0);
    __builtin_amdgcn_s_setprio(0);
    asm volatile("s_barrier" ::: "memory");
    // ---------- P2 ----------
#pragma unroll
    for (int n = 2; n < 4; ++n)
#pragma unroll
      for (int kk = 0; kk < 2; ++kk) {
        const int brow = n * 64 + wc16 + l15;
        bfr[n][kk] = *(const bf16x8*)(Bb + brow * 64 + ((kk * 32 + lg8) ^ ((brow & 7) << 3)));
      }
    if (t + 2 < NT) {
      stB(t + 2, 2); stB(t + 2, 3);
      asm volatile("s_waitcnt vmcnt(4)" ::: "memory");
    } else {
      asm volatile("s_waitcnt vmcnt(0)" ::: "memory");
    }
    asm volatile("s_barrier" ::: "memory");
    asm volatile("s_waitcnt lgkmcnt(0)" ::: "memory");
    __builtin_amdgcn_s_setprio(1);
#pragma unroll
    for (int m = 0; m < 4; ++m)
#pragma unroll
      for (int n = 2; n < 4; ++n)
#pragma unroll
        for (int kk = 0; kk < 2; ++kk)
          acc[m][n] = __builtin_amdgcn_mfma_f32_16x16x32_bf16(af[m][kk], bfr[n][kk], acc[m][n], 0, 0, 0);
    __builtin_amdgcn_s_setprio(0);
    asm volatile("s_barrier" ::: "memory");
  }

  const int cr = (lane >> 4) << 2;
#pragma unroll
  for (int m = 0; m < 4; ++m)
#pragma unroll
    for (int n = 0; n < 4; ++n)
#pragma unroll
      for (int j = 0; j < 4; ++j) {
        const size_t idx = (row0 + wr64 + m * 16 + cr + j) * (size_t)N + col0 + n * 64 + wc16 + l15;
        if constexpr (BF16OUT)
          ((unsigned short*)Cv)[idx] = f2bf(acc[m][n][j]);
        else
          ((float*)Cv)[idx] = acc[m][n][j];
      }
}

// ============ 256x256 deep-pipelined MFMA GEMM (4-phase, BK=64) ============
template <bool BF16OUT>
__global__ __launch_bounds__(512, 2) void gemm256(const unsigned short* __restrict__ Ag,
                                                  const unsigned short* __restrict__ Bg,
                                                  void* __restrict__ Cv,
                                                  int M, int N, int K) {
  __shared__ __align__(16) unsigned short lds[2][32768];
  const int tid = threadIdx.x;
  const int lane = tid & 63;
  const int wave = tid >> 6;
  const int l15 = lane & 15;
  const int lg8 = (lane >> 4) << 3;
  const int wm = (wave >> 2) << 7;
  const int wn = (wave & 3) << 6;

  const int nwg = gridDim.x;
  int wg = ((int)blockIdx.x & 7) * (nwg >> 3) + ((int)blockIdx.x >> 3);
  const int gridM = M >> 8;
  const long row0 = (long)(wg % gridM) << 8;
  const long col0 = (long)(wg / gridM) << 8;

  auto stA = [&](int buf, int kt, int r) {
    const int i = r * 512 + tid;
    const int row = i >> 3;
    const int c = (i & 7) ^ (row & 7);
    stage16(Ag + (size_t)(row0 + row) * K + kt + c * 8, &lds[buf][i * 8]);
  };
  auto stB = [&](int buf, int kt, int r) {
    const int i = r * 512 + tid;
    const int row = i >> 3;
    const int c = (i & 7) ^ (row & 7);
    stage16(Bg + (size_t)(col0 + row) * K + kt + c * 8, &lds[buf][16384 + i * 8]);
  };

  const int NT = K >> 6;
  stB(0, 0, 0); stB(0, 0, 1); stB(0, 0, 2); stB(0, 0, 3);
  stA(0, 0, 0); stA(0, 0, 1); stA(0, 0, 2); stA(0, 0, 3);
  stB(1, 64, 0); stB(1, 64, 1); stB(1, 64, 2); stB(1, 64, 3);
  asm volatile("s_waitcnt vmcnt(4)" ::: "memory");
  asm volatile("s_barrier" ::: "memory");

  f32x4 acc[8][4] = {};
  int cur = 0;
  for (int t = 0; t < NT; ++t, cur ^= 1) {
    const unsigned short* Ab = &lds[cur][0];
    const unsigned short* Bb = &lds[cur][16384];
    bf16x8 af[4][2], bfr[4][2];
    const int ktn = (t + 1) << 6;
    const int ktn2 = (t + 2) << 6;
    // ---------- P1: m0-3 x n0-1 ----------
#pragma unroll
    for (int m = 0; m < 4; ++m)
#pragma unroll
      for (int kk = 0; kk < 2; ++kk) {
        const int row = wm + m * 16 + l15;
        af[m][kk] = *(const bf16x8*)(Ab + row * 64 + ((kk * 32 + lg8) ^ ((row & 7) << 3)));
      }
#pragma unroll
    for (int n = 0; n < 2; ++n)
#pragma unroll
      for (int kk = 0; kk < 2; ++kk) {
        const int brow = wn + n * 16 + l15;
        bfr[n][kk] = *(const bf16x8*)(Bb + brow * 64 + ((kk * 32 + lg8) ^ ((brow & 7) << 3)));
      }
    if (t + 1 < NT) { stA(cur ^ 1, ktn, 0); stA(cur ^ 1, ktn, 1); }
    asm volatile("s_barrier" ::: "memory");
    asm volatile("s_waitcnt lgkmcnt(0)" ::: "memory");
    __builtin_amdgcn_s_setprio(1);
#pragma unroll
    for (int m = 0; m < 4; ++m)
#pragma unroll
      for (int n = 0; n < 2; ++n)
#pragma unroll
        for (int kk = 0; kk < 2; ++kk)
          acc[m][n] = __builtin_amdgcn_mfma_f32_16x16x32_bf16(af[m][kk], bfr[n][kk], acc[m][n], 0, 0, 0);
    __builtin_amdgcn_s_setprio(0);
    asm volatile("s_barrier" ::: "memory");
    // ---------- P2: m0-3 x n2-3 ----------
#pragma unroll
    for (int n = 2; n < 4; ++n)
#pragma unroll
      for (int kk = 0; kk < 2; ++kk) {
        const int brow = wn + n * 16 + l15;
        bfr[n][kk] = *(const bf16x8*)(Bb + brow * 64 + ((kk * 32 + lg8) ^ ((brow & 7) << 3)));
      }
    if (t + 1 < NT) { stA(cur ^ 1, ktn, 2); stA(cur ^ 1, ktn, 3); }
    asm volatile("s_barrier" ::: "memory");
    asm volatile("s_waitcnt lgkmcnt(0)" ::: "memory");
    __builtin_amdgcn_s_setprio(1);
#pragma unroll
    for (int m = 0; m < 4; ++m)
#pragma unroll
      for (int n = 2; n < 4; ++n)
#pragma unroll
        for (int kk = 0; kk < 2; ++kk)
          acc[m][n] = __builtin_amdgcn_mfma_f32_16x16x32_bf16(af[m][kk], bfr[n][kk], acc[m][n], 0, 0, 0);
    __builtin_amdgcn_s_setprio(0);
    asm volatile("s_barrier" ::: "memory");
    // ---------- P3: m4-7 x n0-1 ----------
#pragma unroll
    for (int m = 0; m < 4; ++m)
#pragma unroll
      for (int kk = 0; kk < 2; ++kk) {
        const int row = wm + (m + 4) * 16 + l15;
        af[m][kk] = *(const bf16x8*)(Ab + row * 64 + ((kk * 32 + lg8) ^ ((row & 7) << 3)));
      }
    if (t + 2 < NT) { stB(cur, ktn2, 0); stB(cur, ktn2, 1); }
    asm volatile("s_barrier" ::: "memory");
    asm volatile("s_waitcnt lgkmcnt(0)" ::: "memory");
    __builtin_amdgcn_s_setprio(1);
#pragma unroll
    for (int m = 0; m < 4; ++m)
#pragma unroll
      for (int n = 0; n < 2; ++n)
#pragma unroll
        for (int kk = 0; kk < 2; ++kk)
          acc[m + 4][n] = __builtin_amdgcn_mfma_f32_16x16x32_bf16(af[m][kk], bfr[n][kk], acc[m + 4][n], 0, 0, 0);
    __builtin_amdgcn_s_setprio(0);
    asm volatile("s_barrier" ::: "memory");
    // ---------- P4: m4-7 x n2-3 ----------
    if (t + 2 < NT) { stB(cur, ktn2, 2); stB(cur, ktn2, 3); }
    asm volatile("s_waitcnt vmcnt(4)" ::: "memory");
    asm volatile("s_barrier" ::: "memory");
    __builtin_amdgcn_s_setprio(1);
#pragma unroll
    for (int m = 0; m < 4; ++m)
#pragma unroll
      for (int n = 2; n < 4; ++n)
#pragma unroll
        for (int kk = 0; kk < 2; ++kk)
          acc[m + 4][n] = __builtin_amdgcn_mfma_f32_16x16x32_bf16(af[m][kk], bfr[n][kk], acc[m + 4][n], 0, 0, 0);
    __builtin_amdgcn_s_setprio(0);
    asm volatile("s_barrier" ::: "memory");
  }

  const int cr = (lane >> 4) << 2;
#pragma unroll
  for (int m = 0; m < 8; ++m)
#pragma unroll
    for (int n = 0; n < 4; ++n)
#pragma unroll
      for (int j = 0; j < 4; ++j) {
        const size_t idx = (row0 + wm + m * 16 + cr + j) * (size_t)N + col0 + wn + n * 16 + l15;
        if constexpr (BF16OUT)
          ((unsigned short*)Cv)[idx] = f2bf(acc[m][n][j]);
        else
          ((float*)Cv)[idx] = acc[m][n][j];
      }
}

// ---------------- MFMA masked cross-attention ----------------
__global__ __launch_bounds__(256) void attn2_kernel(
    const unsigned short* __restrict__ qb,
    const unsigned short* __restrict__ kvb,
    const unsigned short* __restrict__ vt,
    const int* __restrict__ img_idx,
    unsigned short* __restrict__ attn_out) {
  __shared__ unsigned short Pl[4][64 * 72];
  const int tid = threadIdx.x;
  const int lane = tid & 63;
  const int w = tid >> 6;
  int bid = blockIdx.x;
  const int hg = bid & 3; bid >>= 2;
  const int tile = bid & 31; bid >>= 5;
  const int b = bid;
  const int t0 = tile * 64;
  const int h = hg * 4 + w;
  const int l15 = lane & 15;
  const int lg = lane >> 4;

  const int* ii = img_idx + b * T_ + t0;
  int myimg = ii[lane];
  int tmin = myimg, tmax = myimg;
#pragma unroll
  for (int off = 1; off < 64; off <<= 1) {
    tmin = min(tmin, __shfl_xor(tmin, off));
    tmax = max(tmax, __shfl_xor(tmax, off));
  }
  unsigned short* op = attn_out + (size_t)(b * T_ + t0) * INNER_ + h * DH_;
  if (tmin < 0) {
    for (int r = 0; r < 64; ++r)
      if (ii[r] < 0) op[(size_t)r * INNER_ + lane] = 0;
  }
  if (tmax < 0) return;

  bf16x8 qa[4][2];
  const unsigned short* qrow = qb + (size_t)(b * T_ + t0) * INNER_ + h * DH_;
#pragma unroll
  for (int m = 0; m < 4; ++m)
#pragma unroll
    for (int kk = 0; kk < 2; ++kk)
      qa[m][kk] = *(const bf16x8*)(qrow + (size_t)(l15 + m * 16) * INNER_ + kk * 32 + lg * 8);

  unsigned short* pw = Pl[w];
  for (int img = max(tmin, 0); img <= tmax; ++img) {
    const unsigned short* Kb = kvb + (size_t)(b * J_ + img * NLAT_) * (2 * INNER_) + h * DH_;
    f32x4 acc[4][4] = {};
#pragma unroll
    for (int kk = 0; kk < 2; ++kk) {
      bf16x8 bfr[4];
#pragma unroll
      for (int n = 0; n < 4; ++n)
        bfr[n] = *(const bf16x8*)(Kb + (size_t)(l15 + n * 16) * (2 * INNER_) + kk * 32 + lg * 8);
#pragma unroll
      for (int m = 0; m < 4; ++m)
#pragma unroll
        for (int n = 0; n < 4; ++n)
          acc[m][n] = __builtin_amdgcn_mfma_f32_16x16x32_bf16(qa[m][kk], bfr[n], acc[m][n], 0, 0, 0);
    }
#pragma unroll
    for (int m = 0; m < 4; ++m) {
#pragma unroll
      for (int j = 0; j < 4; ++j) {
        float mx = fmaxf(fmaxf(acc[m][0][j], acc[m][1][j]), fmaxf(acc[m][2][j], acc[m][3][j]));
#pragma unroll
        for (int off = 1; off < 16; off <<= 1) mx = fmaxf(mx, __shfl_xor(mx, off));
        float sum = 0.f;
#pragma unroll
        for (int n = 0; n < 4; ++n) {
          float e = __expf(acc[m][n][j] - mx);
          acc[m][n][j] = e;
          sum += e;
        }
#pragma unroll
        for (int off = 1; off < 16; off <<= 1) sum += __shfl_xor(sum, off);
        const float ri = 1.0f / sum;
        const int row = m * 16 + lg * 4 + j;
#pragma unroll
        for (int n = 0; n < 4; ++n)
          pw[row * 72 + n * 16 + l15] = f2bf(acc[m][n][j] * ri);
      }
    }
    const unsigned short* Vb = vt + (size_t)(b * INNER_ + h * DH_) * J_ + img * NLAT_;
    f32x4 oacc[4][4] = {};
#pragma unroll
    for (int kk = 0; kk < 2; ++kk) {
      bf16x8 pa[4], bfr[4];
#pragma unroll
      for (int m = 0; m < 4; ++m) {
        bf16x4 lo = *(const bf16x4*)(pw + (m * 16 + l15) * 72 + kk * 32 + lg * 8);
        bf16x4 hi = *(const bf16x4*)(pw + (m * 16 + l15) * 72 + kk * 32 + lg * 8 + 4);
        bf16x8 v;
#pragma unroll
        for (int e = 0; e < 4; ++e) { v[e] = lo[e]; v[e + 4] = hi[e]; }
        pa[m] = v;
      }
#pragma unroll
      for (int n = 0; n < 4; ++n)
        bfr[n] = *(const bf16x8*)(Vb + (size_t)(l15 + n * 16) * J_ + kk * 32 + lg * 8);
#pragma unroll
      for (int m = 0; m < 4; ++m)
#pragma unroll
        for (int n = 0; n < 4; ++n)
          oacc[m][n] = __builtin_amdgcn_mfma_f32_16x16x32_bf16(pa[m], bfr[n], oacc[m][n], 0, 0, 0);
    }
#pragma unroll
    for (int m = 0; m < 4; ++m)
#pragma unroll
      for (int j = 0; j < 4; ++j) {
        const int row = m * 16 + lg * 4 + j;
        if (ii[row] == img) {
#pragma unroll
          for (int n = 0; n < 4; ++n)
            op[(size_t)row * INNER_ + n * 16 + l15] = f2bf(oacc[m][n][j]);
        }
      }
  }
}

extern "C" void kernel_launch(void* const* d_in, const int* in_sizes, int n_in,
                              void* d_out, int out_size, void* d_ws, size_t ws_size,
                              hipStream_t stream) {
  const float* x = (const float*)d_in[0];
  const float* media = (const float*)d_in[1];
  const void* mloc = d_in[2];
  const float* gamma = (const float*)d_in[3];
  const float* beta = (const float*)d_in[4];
  const float* Wq = (const float*)d_in[5];
  const float* Wkv = (const float*)d_in[6];
  const float* Wout = (const float*)d_in[7];
  float* out = (float*)d_out;

  char* ws = (char*)d_ws;
  unsigned short* xn = (unsigned short*)(ws);
  unsigned short* wqt = (unsigned short*)(ws + 33554432);
  unsigned short* wkvt = (unsigned short*)(ws + 37748736);
  unsigned short* woutt = (unsigned short*)(ws + 41943040);
  unsigned short* medb = (unsigned short*)(ws + 46137344);
  unsigned short* qb = (unsigned short*)(ws + 50331648);
  unsigned short* kvb = (unsigned short*)(ws + 67108864);
  unsigned short* vt = (unsigned short*)(ws + 75497472);
  int* img_idx = (int*)(ws + 79691776);
  unsigned short* attn_out = xn;

  // fused prep v2: 2048 ln + 4 scan + 1536 tcast + 1024 cast = 4612 blocks
  prep_kernel<<<4612, 256, 0, stream>>>(x, mloc, gamma, beta, Wq, Wkv, Wout, media,
                                        xn, img_idx, wqt, wkvt, woutt, medb);
  // GEMM1: q = xn @ wqt^T (M=8192,N=1024,K=2048) -> 256 blocks
  gemm_bt2<true><<<(B_ * T_ / 128) * (INNER_ / 256), 512, 0, stream>>>(xn, wqt, qb, B_ * T_, INNER_, D_);
  // GEMM2: kv = medb @ wkvt^T (M=2048,N=2048,K=1024) -> 128 blocks
  gemm_bt2<true><<<(B_ * J_ / 128) * (2 * INNER_ / 256), 512, 0, stream>>>(medb, wkvt, kvb, B_ * J_, 2 * INNER_, DV_);
  vtrans<<<dim3(J_ / 32, INNER_ / 32, B_), dim3(32, 8), 0, stream>>>(kvb, vt);
  attn2_kernel<<<B_ * (T_ / 64) * 4, 256, 0, stream>>>(qb, kvb, vt, img_idx, attn_out);
  // GEMM3: out = attn_out @ woutt^T (M=8192,N=2048,K=1024) -> 256 blocks
  gemm256<false><<<(B_ * T_ / 256) * (D_ / 256), 512, 0, stream>>>(attn_out, woutt, out, B_ * T_, D_, INNER_);
}